// Round 1
// 146.680 us; speedup vs baseline: 1.0026x; 1.0026x over previous
//
#include <hip/hip_runtime.h>

// Problem constants
#define B_    16
#define H_    544
#define W_    960
#define HW    (H_ * W_)          // 522240
#define HW4   (HW / 4)           // 130560 float4 groups per channel plane
#define BLOCK 256
#define G_    2                  // float4 groups of 256 per plane per block
#define BX    255                // blocks per batch: 255 * 512 = 130560 exactly
#define PSTRIDE 256              // padded partials stride per batch (255 used)

// ws layout: three arrays [16][256] floats: sum | bright | dark  (48 KB total)

__global__ __launch_bounds__(BLOCK) void reduce_kernel(
        const float* __restrict__ img, float* __restrict__ ws) {
    const int tid = threadIdx.x;
    const int bx  = blockIdx.x;          // 0..254
    const int b   = blockIdx.y;          // 0..15

    const float4* p0 = (const float4*)(img + (size_t)b * 3 * HW);
    const float4* p1 = p0 + HW4;
    const float4* p2 = p1 + HW4;

    const int base = bx * (G_ * BLOCK) + tid;

    // 6 independent 16B loads — all issued before any use
    float4 va[G_], vc[G_], vd[G_];
    #pragma unroll
    for (int k = 0; k < G_; ++k) va[k] = p0[base + k * BLOCK];
    #pragma unroll
    for (int k = 0; k < G_; ++k) vc[k] = p1[base + k * BLOCK];
    #pragma unroll
    for (int k = 0; k < G_; ++k) vd[k] = p2[base + k * BLOCK];

    const float inv3 = 1.0f / 3.0f;
    float s = 0.0f, br = 0.0f, dk = 0.0f;
    #pragma unroll
    for (int k = 0; k < G_; ++k) {
        float g0 = (va[k].x + vc[k].x + vd[k].x) * inv3;
        float g1 = (va[k].y + vc[k].y + vd[k].y) * inv3;
        float g2 = (va[k].z + vc[k].z + vd[k].z) * inv3;
        float g3 = (va[k].w + vc[k].w + vd[k].w) * inv3;
        s  += g0 + g1 + g2 + g3;
        br += ((g0 >= 0.75f && g0 <= 1.0f) ? 1.0f : 0.0f)
            + ((g1 >= 0.75f && g1 <= 1.0f) ? 1.0f : 0.0f)
            + ((g2 >= 0.75f && g2 <= 1.0f) ? 1.0f : 0.0f)
            + ((g3 >= 0.75f && g3 <= 1.0f) ? 1.0f : 0.0f);
        dk += ((g0 >= 0.0f && g0 < 0.25f) ? 1.0f : 0.0f)
            + ((g1 >= 0.0f && g1 < 0.25f) ? 1.0f : 0.0f)
            + ((g2 >= 0.0f && g2 < 0.25f) ? 1.0f : 0.0f)
            + ((g3 >= 0.0f && g3 < 0.25f) ? 1.0f : 0.0f);
    }

    // Pack the two integer counts into one exact float: per-block br,dk <= 2048,
    // so br + 4096*dk <= 2048 + 2048*4096 < 2^24 — exact integer arithmetic in fp32.
    float bd = br + 4096.0f * dk;

    // wave-64 butterfly reduce (2 chains instead of 3)
    #pragma unroll
    for (int off = 32; off > 0; off >>= 1) {
        s  += __shfl_xor(s,  off);
        bd += __shfl_xor(bd, off);
    }

    __shared__ float sm[2][4];
    const int lane = tid & 63;
    const int wave = tid >> 6;
    if (lane == 0) { sm[0][wave] = s; sm[1][wave] = bd; }
    __syncthreads();

    if (tid == 0) {
        float ts  = sm[0][0] + sm[0][1] + sm[0][2] + sm[0][3];
        float tbd = sm[1][0] + sm[1][1] + sm[1][2] + sm[1][3];
        float td  = floorf(tbd * (1.0f / 4096.0f));   // exact: tbd < 2^24, /2^12 exact
        float tb  = tbd - 4096.0f * td;
        const int slot = b * PSTRIDE + bx;
        ws[slot]                      = ts;
        ws[B_ * PSTRIDE + slot]       = tb;
        ws[2 * B_ * PSTRIDE + slot]   = td;
    }
}

// out layout [5,16]: dr | bright_avg | gaps | e1 | e2
// One block, 256 threads: 16 threads per batch reduce 255 partials each.
__global__ __launch_bounds__(256) void finalize_kernel(
        const float* __restrict__ ws,
        const float* __restrict__ be1,
        const float* __restrict__ be2,
        float* __restrict__ out) {
    __shared__ float s_ba[B_], s_gap[B_];
    const int t   = threadIdx.x;
    const int b   = t >> 4;      // batch 0..15 (16 threads each, 16-aligned in wave)
    const int sub = t & 15;

    const float* ws_s = ws;
    const float* ws_b = ws + B_ * PSTRIDE;
    const float* ws_d = ws + 2 * B_ * PSTRIDE;

    float s = 0.0f, br = 0.0f, dk = 0.0f;
    #pragma unroll
    for (int k = 0; k < 16; ++k) {
        int idx = sub + 16 * k;
        if (idx < BX) {
            s  += ws_s[b * PSTRIDE + idx];
            br += ws_b[b * PSTRIDE + idx];
            dk += ws_d[b * PSTRIDE + idx];
        }
    }
    // reduce within each aligned 16-lane group
    #pragma unroll
    for (int off = 8; off > 0; off >>= 1) {
        s  += __shfl_xor(s,  off);
        br += __shfl_xor(br, off);
        dk += __shfl_xor(dk, off);
    }

    if (sub == 0) {
        float ba = s / (float)HW;
        float dr = br / (dk + 1e-5f);
        // jnp.select: first true wins. BASE_GAP = 0.5
        float gap;
        if (dr > 1.0f && ba > 0.4f && ba < 0.6f)       gap = 1.0f;    // 0.5*2.0
        else if (ba <= 0.3f)                           gap = 0.25f;   // 0.5*0.5
        else if (ba >= 0.7f)                           gap = 0.25f;   // 0.5*0.5
        else if (dr <= 1.0f && ba > 0.3f && ba < 0.7f) gap = 0.375f;  // 0.5*0.75
        else                                           gap = 0.0f;

        out[b]          = dr;
        out[B_ + b]     = ba;
        out[2 * B_ + b] = gap;
        s_ba[b]  = ba;
        s_gap[b] = gap;
    }
    __syncthreads();

    if (t < B_) {
        const float bl = s_ba[B_ - 1];
        const float gl = s_gap[B_ - 1];
        const float SCALE = 1.7f;
        float e1, e2;
        if (bl <= 0.25f) {
            e1 = be1[t] + 0.5f * gl * SCALE;
            e2 = be2[t] + 0.5f * gl * SCALE;
        } else if (bl >= 0.75f) {
            e1 = be1[t] - 0.5f * gl * SCALE;
            e2 = be2[t] - 0.5f * gl * SCALE;
        } else {
            e1 = be1[t] - 0.3f * gl;
            e2 = be2[t] + 0.7f * gl;
        }
        out[3 * B_ + t] = e1;
        out[4 * B_ + t] = e2;
    }
}

extern "C" void kernel_launch(void* const* d_in, const int* in_sizes, int n_in,
                              void* d_out, int out_size, void* d_ws, size_t ws_size,
                              hipStream_t stream) {
    const float* img = (const float*)d_in[0];   // [16,3,544,960] fp32
    const float* be1 = (const float*)d_in[1];   // [16] fp32
    const float* be2 = (const float*)d_in[2];   // [16] fp32
    float* out = (float*)d_out;                 // [5,16] fp32
    float* ws  = (float*)d_ws;                  // uses 48 KB

    reduce_kernel<<<dim3(BX, B_), BLOCK, 0, stream>>>(img, ws);
    finalize_kernel<<<1, 256, 0, stream>>>(ws, be1, be2, out);
}